// Round 1
// 1169.447 us; speedup vs baseline: 1.0023x; 1.0023x over previous
//
#include <hip/hip_runtime.h>

#define N_NODES 20000
#define N_EDGES 640000
#define NODE_NF 256
#define EDGE_NF 128
#define OUT_NF  256

typedef short v8s __attribute__((ext_vector_type(8)));
typedef float v4f __attribute__((ext_vector_type(4)));

__device__ __forceinline__ float bf2f(unsigned short h) {
    unsigned int u = ((unsigned int)h) << 16;
    return __builtin_bit_cast(float, u);
}
__device__ __forceinline__ unsigned short f2bf(float f) {
    unsigned int u = __builtin_bit_cast(unsigned int, f);
    u = (u + 0x7FFFu + ((u >> 16) & 1u)) >> 16;  // round-to-nearest-even
    return (unsigned short)u;
}
// two float4 -> one bf16x8 fragment
__device__ __forceinline__ v8s cvt8(v4f lo, v4f hi) {
    v8s r;
    #pragma unroll
    for (int j = 0; j < 4; ++j) {
        r[j]     = (short)f2bf(lo[j]);
        r[4 + j] = (short)f2bf(hi[j]);
    }
    return r;
}

// ---------------------------------------------------------------------------
// K1: P_i = node_feats @ W_i ; P_j = node_feats @ W_j   (unchanged, ~fast)
// ---------------------------------------------------------------------------
__global__ __launch_bounds__(256) void node_proj_kernel(
    const float* __restrict__ node_feats,
    const float* __restrict__ W_i,
    const float* __restrict__ W_j,
    unsigned short* __restrict__ P_i,
    unsigned short* __restrict__ P_j)
{
    const int n0   = blockIdx.x * 16;          // 20000 = 16 * 1250
    const int wave = threadIdx.x >> 6;
    const int lane = threadIdx.x & 63;
    const int m    = lane & 15;
    const int quad = lane >> 4;

    const float*    W = (wave >= 2) ? W_j : W_i;
    unsigned short* P = (wave >= 2) ? P_j : P_i;
    const int colbase = (wave & 1) * 128;

    v4f acc[8];
    #pragma unroll
    for (int i = 0; i < 8; ++i) acc[i] = (v4f)(0.0f);

    for (int kt = 0; kt < 8; ++kt) {           // K = 256 = 8 * 32
        const int krow = kt * 32 + quad * 8;
        const float* arow = node_feats + (size_t)(n0 + m) * NODE_NF + krow;
        v8s afrag = cvt8(*reinterpret_cast<const v4f*>(arow),
                         *reinterpret_cast<const v4f*>(arow + 4));
        #pragma unroll
        for (int nt = 0; nt < 8; ++nt) {
            const int n = colbase + nt * 16 + m;
            v8s bfrag;
            #pragma unroll
            for (int j = 0; j < 8; ++j)
                bfrag[j] = (short)f2bf(W[(size_t)(krow + j) * OUT_NF + n]);
            acc[nt] = __builtin_amdgcn_mfma_f32_16x16x32_bf16(afrag, bfrag, acc[nt], 0, 0, 0);
        }
    }

    #pragma unroll
    for (int nt = 0; nt < 8; ++nt) {
        const int n = colbase + nt * 16 + m;
        #pragma unroll
        for (int r = 0; r < 4; ++r) {
            const int row = quad * 4 + r;
            P[(size_t)(n0 + row) * OUT_NF + n] = f2bf(acc[nt][r]);
        }
    }
}

// ---------------------------------------------------------------------------
// K2: out[e] = relu(edge_attr[e] @ W_ij + b + P_i[src[e]] + P_j[dst[e]])
// Software-pipelined: double-buffered S (ping-pong), ONE barrier per tile.
// All global loads issued >=1 tile ahead:
//   - edge_index loads 3 tiles ahead (2-deep register rotation)
//   - P gathers 1 tile ahead into registers, staged while S[p] is consumed
//   - edge_attr issued before staging VALU so conversion work hides latency
// This takes the random P-gather latency (the former critical path, inside a
// barrier-ganged region) off the critical path entirely.
// ---------------------------------------------------------------------------
__global__ __launch_bounds__(256) void edge_kernel(
    const float* __restrict__ edge_attr,
    const int*   __restrict__ edge_index,
    const float* __restrict__ W_ij,
    const float* __restrict__ bias,
    const unsigned short* __restrict__ P_i,
    const unsigned short* __restrict__ P_j,
    float*       __restrict__ out,
    int num_tiles)
{
    __shared__ float S[2][16][260];   // stride 260: no epilogue bank conflicts

    const int wave  = threadIdx.x >> 6;
    const int lane  = threadIdx.x & 63;
    const int m     = lane & 15;
    const int quad  = lane >> 4;
    const int wcol0 = wave * 64;

    // Preload W_ij fragments (K=128 -> 4 ktiles; wave covers 64 cols -> 4 ntiles)
    v8s wf[4][4];
    #pragma unroll
    for (int kt = 0; kt < 4; ++kt) {
        const int krow = kt * 32 + quad * 8;
        #pragma unroll
        for (int nt = 0; nt < 4; ++nt) {
            const int n = wcol0 + nt * 16 + m;
            #pragma unroll
            for (int j = 0; j < 8; ++j)
                wf[kt][nt][j] = (short)f2bf(W_ij[(size_t)(krow + j) * OUT_NF + n]);
        }
    }

    // staging mapping: thread covers 16 cols of one edge row
    const int s_edge = threadIdx.x & 15;         // 0..15
    const int s_c0   = (threadIdx.x >> 4) * 16;  // 0,16,...,240

    // bias for this thread's 16 staging columns, preloaded once
    v4f brg[4];
    #pragma unroll
    for (int i = 0; i < 4; ++i)
        brg[i] = *reinterpret_cast<const v4f*>(bias + s_c0 + 4 * i);

    const int stride = gridDim.x;
    const int tile0  = blockIdx.x;
    if (tile0 >= num_tiles) return;

    // pipeline tile ids: tB = t+1, tC = t+2, tD = t+3 (clamped to tile0: safe re-gather)
    int tB = tile0 + stride;     if (tB >= num_tiles) tB = tile0;
    int tC = tile0 + 2 * stride; if (tC >= num_tiles) tC = tile0;
    int tD = tile0 + 3 * stride; if (tD >= num_tiles) tD = tile0;

    // ---- prologue: idx for t0 / t+1 / t+2, gather+stage P(t0), issue P(t+1) ----
    int srcA = edge_index[tile0 * 16 + s_edge];
    int dstA = edge_index[N_EDGES + tile0 * 16 + s_edge];
    int srcB = edge_index[tB * 16 + s_edge];
    int dstB = edge_index[N_EDGES + tB * 16 + s_edge];
    int srcC = edge_index[tC * 16 + s_edge];
    int dstC = edge_index[N_EDGES + tC * 16 + s_edge];

    v8s pi0, pi1, pj0, pj1;
    {
        const unsigned short* pp = P_i + (size_t)srcA * OUT_NF + s_c0;
        const unsigned short* qq = P_j + (size_t)dstA * OUT_NF + s_c0;
        pi0 = *reinterpret_cast<const v8s*>(pp);
        pi1 = *reinterpret_cast<const v8s*>(pp + 8);
        pj0 = *reinterpret_cast<const v8s*>(qq);
        pj1 = *reinterpret_cast<const v8s*>(qq + 8);
    }
    #pragma unroll
    for (int c = 0; c < 4; ++c) {
        S[0][s_edge][s_c0 + c]      = bf2f((unsigned short)pi0[c])     + bf2f((unsigned short)pj0[c])     + brg[0][c];
        S[0][s_edge][s_c0 + 4 + c]  = bf2f((unsigned short)pi0[4 + c]) + bf2f((unsigned short)pj0[4 + c]) + brg[1][c];
        S[0][s_edge][s_c0 + 8 + c]  = bf2f((unsigned short)pi1[c])     + bf2f((unsigned short)pj1[c])     + brg[2][c];
        S[0][s_edge][s_c0 + 12 + c] = bf2f((unsigned short)pi1[4 + c]) + bf2f((unsigned short)pj1[4 + c]) + brg[3][c];
    }
    {   // issue P gathers for tile t+1 (consumed next iteration's staging)
        const unsigned short* pp = P_i + (size_t)srcB * OUT_NF + s_c0;
        const unsigned short* qq = P_j + (size_t)dstB * OUT_NF + s_c0;
        pi0 = *reinterpret_cast<const v8s*>(pp);
        pi1 = *reinterpret_cast<const v8s*>(pp + 8);
        pj0 = *reinterpret_cast<const v8s*>(qq);
        pj1 = *reinterpret_cast<const v8s*>(qq + 8);
    }
    __syncthreads();

    // ---- main loop: one barrier per tile ----
    int i = 0;
    for (int t = tile0; t < num_tiles; t += stride, ++i) {
        const int p  = i & 1;
        const int e0 = t * 16;

        // (a) issue idx loads for tile t+3
        int srcD = edge_index[tD * 16 + s_edge];
        int dstD = edge_index[N_EDGES + tD * 16 + s_edge];

        // (b) issue edge_attr loads for tile t (latency hidden by staging VALU)
        v4f ea[4][2];
        #pragma unroll
        for (int kt = 0; kt < 4; ++kt) {
            const float* arow = edge_attr + (size_t)(e0 + m) * EDGE_NF + kt * 32 + quad * 8;
            ea[kt][0] = *reinterpret_cast<const v4f*>(arow);
            ea[kt][1] = *reinterpret_cast<const v4f*>(arow + 4);
        }

        // (c) stage S[p^1] <- P(t+1) regs (gathered last iteration)
        #pragma unroll
        for (int c = 0; c < 4; ++c) {
            S[p ^ 1][s_edge][s_c0 + c]      = bf2f((unsigned short)pi0[c])     + bf2f((unsigned short)pj0[c])     + brg[0][c];
            S[p ^ 1][s_edge][s_c0 + 4 + c]  = bf2f((unsigned short)pi0[4 + c]) + bf2f((unsigned short)pj0[4 + c]) + brg[1][c];
            S[p ^ 1][s_edge][s_c0 + 8 + c]  = bf2f((unsigned short)pi1[c])     + bf2f((unsigned short)pj1[c])     + brg[2][c];
            S[p ^ 1][s_edge][s_c0 + 12 + c] = bf2f((unsigned short)pi1[4 + c]) + bf2f((unsigned short)pj1[4 + c]) + brg[3][c];
        }

        // (d) issue P gathers for tile t+2 (idx loaded 2 iterations ago)
        {
            const unsigned short* pp = P_i + (size_t)srcC * OUT_NF + s_c0;
            const unsigned short* qq = P_j + (size_t)dstC * OUT_NF + s_c0;
            pi0 = *reinterpret_cast<const v8s*>(pp);
            pi1 = *reinterpret_cast<const v8s*>(pp + 8);
            pj0 = *reinterpret_cast<const v8s*>(qq);
            pj1 = *reinterpret_cast<const v8s*>(qq + 8);
        }

        // (e) MFMA: [16 edges x 128] @ [128 x 256]
        v4f acc[4];
        #pragma unroll
        for (int k = 0; k < 4; ++k) acc[k] = (v4f)(0.0f);
        #pragma unroll
        for (int kt = 0; kt < 4; ++kt) {
            v8s afrag = cvt8(ea[kt][0], ea[kt][1]);
            #pragma unroll
            for (int nt = 0; nt < 4; ++nt)
                acc[nt] = __builtin_amdgcn_mfma_f32_16x16x32_bf16(afrag, wf[kt][nt], acc[nt], 0, 0, 0);
        }

        // (f) epilogue: add S[p], relu, fp32 store
        #pragma unroll
        for (int nt = 0; nt < 4; ++nt) {
            const int col = wcol0 + nt * 16 + m;
            #pragma unroll
            for (int r = 0; r < 4; ++r) {
                const int row = quad * 4 + r;
                float v = acc[nt][r] + S[p][row][col];
                v = v > 0.0f ? v : 0.0f;
                out[(size_t)(e0 + row) * OUT_NF + col] = v;
            }
        }

        // (g) single barrier: S[p^1] published, S[p] release for next staging
        __syncthreads();

        srcC = srcD; dstC = dstD;
        tD += stride; if (tD >= num_tiles) tD = tile0;
    }
}

extern "C" void kernel_launch(void* const* d_in, const int* in_sizes, int n_in,
                              void* d_out, int out_size, void* d_ws, size_t ws_size,
                              hipStream_t stream) {
    const float* node_feats = (const float*)d_in[0]; // [20000,256] fp32
    const int*   edge_index = (const int*)d_in[1];   // [2,640000] int32
    const float* edge_attr  = (const float*)d_in[2]; // [640000,128] fp32
    const float* W_ij       = (const float*)d_in[3]; // [128,256] fp32
    const float* b_ij       = (const float*)d_in[4]; // [256] fp32
    const float* W_i        = (const float*)d_in[5]; // [256,256] fp32
    const float* W_j        = (const float*)d_in[6]; // [256,256] fp32
    float*       out        = (float*)d_out;         // [640000,256] fp32

    unsigned short* P_i = (unsigned short*)d_ws;                  // 10.24 MB bf16
    unsigned short* P_j = P_i + (size_t)N_NODES * OUT_NF;         // 10.24 MB bf16

    node_proj_kernel<<<N_NODES / 16, 256, 0, stream>>>(node_feats, W_i, W_j, P_i, P_j);
    edge_kernel<<<2560, 256, 0, stream>>>(edge_attr, edge_index, W_ij, b_ij,
                                          P_i, P_j, out, N_EDGES / 16);
}

// Round 2
// 1106.121 us; speedup vs baseline: 1.0597x; 1.0573x over previous
//
#include <hip/hip_runtime.h>

#define N_NODES 20000
#define N_EDGES 640000
#define NODE_NF 256
#define EDGE_NF 128
#define OUT_NF  256

typedef short v8s __attribute__((ext_vector_type(8)));
typedef short v4s __attribute__((ext_vector_type(4)));
typedef float v4f __attribute__((ext_vector_type(4)));

__device__ __forceinline__ float bf2f(unsigned short h) {
    unsigned int u = ((unsigned int)h) << 16;
    return __builtin_bit_cast(float, u);
}
__device__ __forceinline__ unsigned short f2bf(float f) {
    unsigned int u = __builtin_bit_cast(unsigned int, f);
    u = (u + 0x7FFFu + ((u >> 16) & 1u)) >> 16;  // round-to-nearest-even
    return (unsigned short)u;
}
// two float4 -> one bf16x8 fragment
__device__ __forceinline__ v8s cvt8(v4f lo, v4f hi) {
    v8s r;
    #pragma unroll
    for (int j = 0; j < 4; ++j) {
        r[j]     = (short)f2bf(lo[j]);
        r[4 + j] = (short)f2bf(hi[j]);
    }
    return r;
}

// ---------------------------------------------------------------------------
// K1: P_i = node_feats @ W_i ; P_j = node_feats @ W_j
// Output written in CONSUMER-SWIZZLED layout:
//   P'[node][ (c>>6)*64 + (c&15)*4 + ((c>>4)&3) ] = P[node][c]
// so that K2's epilogue thread (m,quad,wave) reads its 4 needed columns
// {w*64 + nt*16 + m : nt=0..3} as ONE contiguous v4s (8B) load.
// Epilogue packs nt-groups into v4s -> 16 lanes x 8B = 128B coalesced stores.
// ---------------------------------------------------------------------------
__global__ __launch_bounds__(256) void node_proj_kernel(
    const float* __restrict__ node_feats,
    const float* __restrict__ W_i,
    const float* __restrict__ W_j,
    unsigned short* __restrict__ P_i,
    unsigned short* __restrict__ P_j)
{
    const int n0   = blockIdx.x * 16;          // 20000 = 16 * 1250
    const int wave = threadIdx.x >> 6;
    const int lane = threadIdx.x & 63;
    const int m    = lane & 15;
    const int quad = lane >> 4;

    const float*    W = (wave >= 2) ? W_j : W_i;
    unsigned short* P = (wave >= 2) ? P_j : P_i;
    const int colbase = (wave & 1) * 128;

    v4f acc[8];
    #pragma unroll
    for (int i = 0; i < 8; ++i) acc[i] = (v4f)(0.0f);

    for (int kt = 0; kt < 8; ++kt) {           // K = 256 = 8 * 32
        const int krow = kt * 32 + quad * 8;
        const float* arow = node_feats + (size_t)(n0 + m) * NODE_NF + krow;
        v8s afrag = cvt8(*reinterpret_cast<const v4f*>(arow),
                         *reinterpret_cast<const v4f*>(arow + 4));
        #pragma unroll
        for (int nt = 0; nt < 8; ++nt) {
            const int n = colbase + nt * 16 + m;
            v8s bfrag;
            #pragma unroll
            for (int j = 0; j < 8; ++j)
                bfrag[j] = (short)f2bf(W[(size_t)(krow + j) * OUT_NF + n]);
            acc[nt] = __builtin_amdgcn_mfma_f32_16x16x32_bf16(afrag, bfrag, acc[nt], 0, 0, 0);
        }
    }

    // C/D layout: col = colbase + nt*16 + m, row = quad*4 + r.
    // Swizzled write: for nt in 0..3 -> p = colbase      + m*4 + nt
    //                 for nt in 4..7 -> p = colbase + 64 + m*4 + (nt-4)
    #pragma unroll
    for (int r = 0; r < 4; ++r) {
        const int row = quad * 4 + r;
        v4s lo, hi;
        #pragma unroll
        for (int nt = 0; nt < 4; ++nt) {
            lo[nt] = (short)f2bf(acc[nt][r]);
            hi[nt] = (short)f2bf(acc[nt + 4][r]);
        }
        unsigned short* base = P + (size_t)(n0 + row) * OUT_NF + colbase + m * 4;
        *reinterpret_cast<v4s*>(base)      = lo;
        *reinterpret_cast<v4s*>(base + 64) = hi;
    }
}

// ---------------------------------------------------------------------------
// K2: out[e] = relu(edge_attr[e] @ W_ij + b + P_i[src[e]] + P_j[dst[e]])
// BARRIER-FREE / LDS-FREE. Each wave independently owns (tile, 64-col slice):
// the 4 waves of a block process the same 16-edge tile's four col-slices
// (sharing edge_attr rows via L1) but never synchronize. The P gather reads
// the consumer-swizzled P' tables: one v4s (8B) per (edge, table) per thread,
// 128B coalesced per quad. P values go straight into the epilogue add —
// no LDS redistribution, no staging VALU, no vmcnt-drain barriers.
// Nontemporal output stores keep the 655MB out-stream from evicting the
// 20.5MB P tables out of LLC.
// ---------------------------------------------------------------------------
__global__ __launch_bounds__(256, 4) void edge_kernel(
    const float* __restrict__ edge_attr,
    const int*   __restrict__ edge_index,
    const float* __restrict__ W_ij,
    const float* __restrict__ bias,
    const unsigned short* __restrict__ P_i,
    const unsigned short* __restrict__ P_j,
    float*       __restrict__ out,
    int num_tiles)
{
    const int wave  = threadIdx.x >> 6;
    const int lane  = threadIdx.x & 63;
    const int m     = lane & 15;
    const int quad  = lane >> 4;
    const int wcol0 = wave * 64;

    // Preload W_ij fragments (K=128 -> 4 ktiles; wave covers 64 cols -> 4 ntiles)
    v8s wf[4][4];
    #pragma unroll
    for (int kt = 0; kt < 4; ++kt) {
        const int krow = kt * 32 + quad * 8;
        #pragma unroll
        for (int nt = 0; nt < 4; ++nt) {
            const int n = wcol0 + nt * 16 + m;
            #pragma unroll
            for (int j = 0; j < 8; ++j)
                wf[kt][nt][j] = (short)f2bf(W_ij[(size_t)(krow + j) * OUT_NF + n]);
        }
    }

    // bias for this thread's 4 accumulator columns
    float bv[4];
    #pragma unroll
    for (int nt = 0; nt < 4; ++nt)
        bv[nt] = bias[wcol0 + nt * 16 + m];

    for (int t = blockIdx.x; t < num_tiles; t += gridDim.x) {
        const int e0 = t * 16;

        // ---- issue edge_attr loads (consumed by MFMA below) ----
        v4f ea[4][2];
        #pragma unroll
        for (int kt = 0; kt < 4; ++kt) {
            const float* arow = edge_attr + (size_t)(e0 + m) * EDGE_NF + kt * 32 + quad * 8;
            ea[kt][0] = *reinterpret_cast<const v4f*>(arow);
            ea[kt][1] = *reinterpret_cast<const v4f*>(arow + 4);
        }

        // ---- issue idx + swizzled P gathers (consumed in epilogue, hidden
        //      under cvt+MFMA) ----
        v4s pi4[4], pj4[4];
        #pragma unroll
        for (int r = 0; r < 4; ++r) {
            const int e  = e0 + quad * 4 + r;
            const int s  = edge_index[e];
            const int d  = edge_index[N_EDGES + e];
            pi4[r] = *reinterpret_cast<const v4s*>(P_i + (size_t)s * OUT_NF + wcol0 + m * 4);
            pj4[r] = *reinterpret_cast<const v4s*>(P_j + (size_t)d * OUT_NF + wcol0 + m * 4);
        }

        // ---- MFMA: [16 edges x 128] @ [128 x 64] ----
        v4f acc[4];
        #pragma unroll
        for (int k = 0; k < 4; ++k) acc[k] = (v4f)(0.0f);
        #pragma unroll
        for (int kt = 0; kt < 4; ++kt) {
            v8s afrag = cvt8(ea[kt][0], ea[kt][1]);
            #pragma unroll
            for (int nt = 0; nt < 4; ++nt)
                acc[nt] = __builtin_amdgcn_mfma_f32_16x16x32_bf16(afrag, wf[kt][nt], acc[nt], 0, 0, 0);
        }

        // ---- epilogue: direct add of gathered P' values, relu, nt-store ----
        #pragma unroll
        for (int r = 0; r < 4; ++r) {
            const int row = quad * 4 + r;
            float* orow = out + (size_t)(e0 + row) * OUT_NF + wcol0 + m;
            #pragma unroll
            for (int nt = 0; nt < 4; ++nt) {
                float v = acc[nt][r]
                        + bf2f((unsigned short)pi4[r][nt])
                        + bf2f((unsigned short)pj4[r][nt])
                        + bv[nt];
                v = v > 0.0f ? v : 0.0f;
                __builtin_nontemporal_store(v, orow + nt * 16);
            }
        }
    }
}

extern "C" void kernel_launch(void* const* d_in, const int* in_sizes, int n_in,
                              void* d_out, int out_size, void* d_ws, size_t ws_size,
                              hipStream_t stream) {
    const float* node_feats = (const float*)d_in[0]; // [20000,256] fp32
    const int*   edge_index = (const int*)d_in[1];   // [2,640000] int32
    const float* edge_attr  = (const float*)d_in[2]; // [640000,128] fp32
    const float* W_ij       = (const float*)d_in[3]; // [128,256] fp32
    const float* b_ij       = (const float*)d_in[4]; // [256] fp32
    const float* W_i        = (const float*)d_in[5]; // [256,256] fp32
    const float* W_j        = (const float*)d_in[6]; // [256,256] fp32
    float*       out        = (float*)d_out;         // [640000,256] fp32

    unsigned short* P_i = (unsigned short*)d_ws;                  // 10.24 MB bf16 (swizzled)
    unsigned short* P_j = P_i + (size_t)N_NODES * OUT_NF;         // 10.24 MB bf16 (swizzled)

    node_proj_kernel<<<N_NODES / 16, 256, 0, stream>>>(node_feats, W_i, W_j, P_i, P_j);
    edge_kernel<<<1024, 256, 0, stream>>>(edge_attr, edge_index, W_ij, b_ij,
                                          P_i, P_j, out, N_EDGES / 16);
}